// Round 10
// baseline (180.163 us; speedup 1.0000x reference)
//
#include <hip/hip_runtime.h>
#include <hip/hip_bf16.h>
#include <stdint.h>

// Problem constants: B=2, H=16, S=2048, D=64, fp32 in/out.
#define BB 2
#define HH 16
#define SS 2048
#define DD 64
constexpr int BH = BB * HH;
constexpr int NT = SS / 64;    // 32 K-tiles

typedef _Float16 f16_t;
typedef f16_t f16x8 __attribute__((ext_vector_type(8)));
typedef float f32x4 __attribute__((ext_vector_type(4)));

__device__ __forceinline__ uint32_t pkf16(float a, float b) {
    // two fp32 -> packed f16x2 (v_cvt_pkrtz_f16_f32), as raw dword
    return __builtin_bit_cast(uint32_t, __builtin_amdgcn_cvt_pkrtz(a, b));
}

// ---------- Single fused kernel: transposed-S fp16 flash attention ----------
// Block (bh, qt) owns 64 q-rows; K-loop stages each 64-key tile from global
// with in-kernel fp32->f16 convert (K) and transpose+mask-fold (V).
// S^T = K·Q^T  => lane's 16 S values all belong to q = l16 (in-lane softmax).
// O^T = V^T·P^T; all MFMA operand frags are contiguous LDS rows.
__global__ __launch_bounds__(256)
void fattn5(const float* __restrict__ Qg, const float* __restrict__ Kg,
            const float* __restrict__ Vg, const float* __restrict__ Mg,
            const float* __restrict__ Sg, float* __restrict__ Og)
{
    __shared__ __align__(16) f16_t Kh_lds[64][72];
    __shared__ __align__(16) f16_t Vt_lds[64][72];       // V^T: [d][key]
    __shared__ __align__(16) f16_t Pt_lds[4][16][72];    // per-wave: [q=l16][key]
    __shared__ float msk_lds[SS];                         // full mask row of b (8KB)

    const int bh   = blockIdx.x % BH;      // bh-minor => XCD affinity
    const int qt   = blockIdx.x / BH;      // 0..31
    const int b    = bh / HH;
    const int tid  = threadIdx.x;
    const int wave = tid >> 6;
    const int lane = tid & 63;
    const int l16  = lane & 15;
    const int quad = lane >> 4;

    const float sc = Sg[b] * 1.44269504088896340736f;  // scale*log2e, folded into Q
    const size_t base = (size_t)bh * SS * DD;
    const int q0 = qt * 64 + wave * 16;

    // ---- Preload full mask row (coalesced; visible after iter-0's barrier) ----
    for (int i = tid; i < SS; i += 256) msk_lds[i] = Mg[(size_t)b * SS + i];

    // ---- Q fragments (B-operand layout), fp16 of (q * sc) ----
    f16x8 qf[2];
    {
        const float* qp = Qg + base + (size_t)(q0 + l16) * DD + quad * 8;
#pragma unroll
        for (int kc = 0; kc < 2; ++kc) {
            float4 a  = *(const float4*)(qp + kc * 32);
            float4 b4 = *(const float4*)(qp + kc * 32 + 4);
            f16x8 f;
            f[0] = (f16_t)(a.x * sc);  f[1] = (f16_t)(a.y * sc);
            f[2] = (f16_t)(a.z * sc);  f[3] = (f16_t)(a.w * sc);
            f[4] = (f16_t)(b4.x * sc); f[5] = (f16_t)(b4.y * sc);
            f[6] = (f16_t)(b4.z * sc); f[7] = (f16_t)(b4.w * sc);
            qf[kc] = f;
        }
    }

    f32x4 Ot[4];                // O^T: D[m=d=mt*16+quad*4+r][n=q=l16]
#pragma unroll
    for (int mt = 0; mt < 4; ++mt) Ot[mt] = f32x4{0.f, 0.f, 0.f, 0.f};
    float m_run = -1e30f, l_run = 0.0f;

    // Staging thread mappings
    const int krow = tid >> 2;             // K: row 0..63
    const int kcol = (tid & 3) * 16;       // K: 16-col chunk
    const int vd   = tid & 63;             // V: d column (coalesced across lanes)
    const int vk0  = wave * 16;            // V: 16-key chunk per wave

    for (int kt = 0; kt < NT; ++kt) {
        __syncthreads();   // prev iteration's frag reads done (and msk ready at kt=0)

        // ---- Stage K tile: fp32 load -> f16 -> LDS (coalesced) ----
        {
            const float* kp = Kg + base + (size_t)(kt * 64 + krow) * DD + kcol;
            float4 a0 = *(const float4*)(kp);
            float4 a1 = *(const float4*)(kp + 4);
            float4 a2 = *(const float4*)(kp + 8);
            float4 a3 = *(const float4*)(kp + 12);
            uint4 w0 = make_uint4(pkf16(a0.x, a0.y), pkf16(a0.z, a0.w),
                                  pkf16(a1.x, a1.y), pkf16(a1.z, a1.w));
            uint4 w1 = make_uint4(pkf16(a2.x, a2.y), pkf16(a2.z, a2.w),
                                  pkf16(a3.x, a3.y), pkf16(a3.z, a3.w));
            *(uint4*)&Kh_lds[krow][kcol]     = w0;
            *(uint4*)&Kh_lds[krow][kcol + 8] = w1;
        }
        // ---- Stage V^T tile: 16 coalesced dword loads, mask fold, b64 LDS writes ----
        {
            const float* vp = Vg + base + (size_t)(kt * 64 + vk0) * DD + vd;
            const float* mp = &msk_lds[kt * 64 + vk0];
#pragma unroll
            for (int j = 0; j < 4; ++j) {
                float v0 = vp[(4 * j + 0) * DD] * mp[4 * j + 0];
                float v1 = vp[(4 * j + 1) * DD] * mp[4 * j + 1];
                float v2 = vp[(4 * j + 2) * DD] * mp[4 * j + 2];
                float v3 = vp[(4 * j + 3) * DD] * mp[4 * j + 3];
                uint2 w = make_uint2(pkf16(v0, v1), pkf16(v2, v3));
                *(uint2*)&Vt_lds[vd][vk0 + 4 * j] = w;
            }
        }
        __syncthreads();

        // ---- S^T = K Q^T ----
        f32x4 Sfr[4];
#pragma unroll
        for (int mt = 0; mt < 4; ++mt) {
            f32x4 acc = f32x4{0.f, 0.f, 0.f, 0.f};
#pragma unroll
            for (int kc = 0; kc < 2; ++kc) {
                f16x8 kh = *(const f16x8*)&Kh_lds[mt * 16 + l16][kc * 32 + quad * 8];
                acc = __builtin_amdgcn_mfma_f32_16x16x32_f16(kh, qf[kc], acc, 0, 0, 0);
            }
            Sfr[mt] = acc;   // D[m=key][n=q=l16], pre-scaled (sc in Q)
        }

        // ---- Online softmax: 16 in-lane values (q = l16) ----
        float mx = Sfr[0][0];
#pragma unroll
        for (int mt = 0; mt < 4; ++mt)
#pragma unroll
            for (int r = 0; r < 4; ++r) mx = fmaxf(mx, Sfr[mt][r]);
        mx = fmaxf(mx, __shfl_xor(mx, 16));
        mx = fmaxf(mx, __shfl_xor(mx, 32));

        if (__any(mx > m_run)) {
            const float mnew  = fmaxf(m_run, mx);
            const float alpha = exp2f(m_run - mnew);
            m_run = mnew;
            l_run *= alpha;
#pragma unroll
            for (int mt = 0; mt < 4; ++mt) Ot[mt] *= alpha;
        }

        float ps[4][4];
        float rs = 0.0f;
#pragma unroll
        for (int mt = 0; mt < 4; ++mt)
#pragma unroll
            for (int r = 0; r < 4; ++r) {
                ps[mt][r] = exp2f(Sfr[mt][r] - m_run);
                rs += ps[mt][r];
            }
        rs += __shfl_xor(rs, 16);
        rs += __shfl_xor(rs, 32);
        l_run += rs;

        // ---- P^T -> LDS: packed f16 pairs, 4x ds_write_b64 ----
#pragma unroll
        for (int mt = 0; mt < 4; ++mt) {
            uint2 w = make_uint2(pkf16(ps[mt][0], ps[mt][1]),
                                 pkf16(ps[mt][2], ps[mt][3]));
            *(uint2*)&Pt_lds[wave][l16][mt * 16 + quad * 4] = w;
        }
        // Pt_lds is per-wave private; in-wave RAW handled by lgkmcnt.

        // ---- O^T += V^T P^T ----
#pragma unroll
        for (int kc = 0; kc < 2; ++kc) {
            f16x8 pf = *(const f16x8*)&Pt_lds[wave][l16][kc * 32 + quad * 8];
#pragma unroll
            for (int mt = 0; mt < 4; ++mt) {
                f16x8 vf = *(const f16x8*)&Vt_lds[mt * 16 + l16][kc * 32 + quad * 8];
                Ot[mt] = __builtin_amdgcn_mfma_f32_16x16x32_f16(vf, pf, Ot[mt], 0, 0, 0);
            }
        }
    }

    // ---- Epilogue: O[q][d] = O^T[d][q] / l ----
    const float inv = 1.0f / l_run;
    float* op = Og + base + (size_t)(q0 + l16) * DD + quad * 4;
#pragma unroll
    for (int mt = 0; mt < 4; ++mt) {
#pragma unroll
        for (int r = 0; r < 4; ++r)
            op[mt * 16 + r] = Ot[mt][r] * inv;
    }
}

extern "C" void kernel_launch(void* const* d_in, const int* in_sizes, int n_in,
                              void* d_out, int out_size, void* d_ws, size_t ws_size,
                              hipStream_t stream) {
    const float* Qg = (const float*)d_in[0];
    const float* Kg = (const float*)d_in[1];
    const float* Vg = (const float*)d_in[2];
    // d_in[3] = query_mask (all ones, unused by reference)
    const float* Mg = (const float*)d_in[4];  // key_mask [B,1,1,S]
    const float* Sg = (const float*)d_in[5];  // scale_factor [B,1,1,1]
    // d_in[6] = dropout (0, identity)
    float* Og = (float*)d_out;

    fattn5<<<dim3(BH * NT), dim3(256), 0, stream>>>(Qg, Kg, Vg, Mg, Sg, Og);
}

// Round 11
// 169.004 us; speedup vs baseline: 1.0660x; 1.0660x over previous
//
#include <hip/hip_runtime.h>
#include <hip/hip_bf16.h>
#include <stdint.h>

// Problem constants: B=2, H=16, S=2048, D=64, fp32 in/out.
#define BB 2
#define HH 16
#define SS 2048
#define DD 64
constexpr int BH = BB * HH;
constexpr int NT = SS / 64;    // 32 K-tiles
constexpr int QB = 16;         // q-tiles of 128 => 16 blocks per bh

typedef _Float16 f16_t;
typedef f16_t f16x8 __attribute__((ext_vector_type(8)));
typedef float f32x4 __attribute__((ext_vector_type(4)));

__device__ __forceinline__ uint32_t pkf16(float a, float b) {
    // two fp32 -> packed f16x2 (v_cvt_pkrtz_f16_f32), as raw dword
    return __builtin_bit_cast(uint32_t, __builtin_amdgcn_cvt_pkrtz(a, b));
}

// ---------- Single fused kernel: transposed-S fp16 flash attention ----------
// Block (bh, qt) owns 128 q-rows with 8 waves (16 q each); K-loop stages each
// 64-key tile once per block (16x redundancy per bh instead of 32x -> the
// L2/L3 re-read traffic, measured at ~85us/GB, halves).
// S^T = K.Q^T => lane's 16 S values all belong to q = l16 (in-lane softmax).
// O^T = V^T.P^T; all MFMA operand frags are contiguous LDS rows.
__global__ __launch_bounds__(512)
void fattn6(const float* __restrict__ Qg, const float* __restrict__ Kg,
            const float* __restrict__ Vg, const float* __restrict__ Mg,
            const float* __restrict__ Sg, float* __restrict__ Og)
{
    __shared__ __align__(16) f16_t Kh_lds[64][72];
    __shared__ __align__(16) f16_t Vt_lds[64][72];       // V^T: [d][key]
    __shared__ __align__(16) f16_t Pt_lds[8][16][72];    // per-wave: [q=l16][key]
    __shared__ float msk_lds[SS];                         // full mask row of b (8KB)

    const int bh   = blockIdx.x % BH;      // bh-minor => XCD affinity
    const int qt   = blockIdx.x / BH;      // 0..15
    const int b    = bh / HH;
    const int tid  = threadIdx.x;
    const int wave = tid >> 6;             // 0..7
    const int lane = tid & 63;
    const int l16  = lane & 15;
    const int quad = lane >> 4;

    const float sc = Sg[b] * 1.44269504088896340736f;  // scale*log2e, folded into Q
    const size_t base = (size_t)bh * SS * DD;
    const int q0 = qt * 128 + wave * 16;

    // ---- Preload full mask row (coalesced; visible after iter-0's barrier) ----
    for (int i = tid; i < SS; i += 512) msk_lds[i] = Mg[(size_t)b * SS + i];

    // ---- Q fragments (B-operand layout), fp16 of (q * sc) ----
    f16x8 qf[2];
    {
        const float* qp = Qg + base + (size_t)(q0 + l16) * DD + quad * 8;
#pragma unroll
        for (int kc = 0; kc < 2; ++kc) {
            float4 a  = *(const float4*)(qp + kc * 32);
            float4 b4 = *(const float4*)(qp + kc * 32 + 4);
            f16x8 f;
            f[0] = (f16_t)(a.x * sc);  f[1] = (f16_t)(a.y * sc);
            f[2] = (f16_t)(a.z * sc);  f[3] = (f16_t)(a.w * sc);
            f[4] = (f16_t)(b4.x * sc); f[5] = (f16_t)(b4.y * sc);
            f[6] = (f16_t)(b4.z * sc); f[7] = (f16_t)(b4.w * sc);
            qf[kc] = f;
        }
    }

    f32x4 Ot[4];                // O^T: D[m=d=mt*16+quad*4+r][n=q=l16]
#pragma unroll
    for (int mt = 0; mt < 4; ++mt) Ot[mt] = f32x4{0.f, 0.f, 0.f, 0.f};
    float m_run = -1e30f, l_run = 0.0f;

    // Staging thread mappings (512 threads)
    const int krow = tid >> 3;             // K: row 0..63
    const int kc8  = (tid & 7) * 8;        // K: 8-col chunk
    const int vd   = tid & 63;             // V: d column (coalesced across lanes)
    const int vk0  = (tid >> 6) * 8;       // V: 8-key chunk per wave

    for (int kt = 0; kt < NT; ++kt) {
        __syncthreads();   // prev iteration's frag reads done (and msk ready at kt=0)

        // ---- Stage K tile: 2x float4 -> 8 f16 -> one b128 LDS write ----
        {
            const float* kp = Kg + base + (size_t)(kt * 64 + krow) * DD + kc8;
            float4 a0 = *(const float4*)(kp);
            float4 a1 = *(const float4*)(kp + 4);
            uint4 w = make_uint4(pkf16(a0.x, a0.y), pkf16(a0.z, a0.w),
                                 pkf16(a1.x, a1.y), pkf16(a1.z, a1.w));
            *(uint4*)&Kh_lds[krow][kc8] = w;
        }
        // ---- Stage V^T tile: 8 coalesced dword loads, mask fold, one b128 write ----
        {
            const float* vp = Vg + base + (size_t)(kt * 64 + vk0) * DD + vd;
            const float* mp = &msk_lds[kt * 64 + vk0];
            float v0 = vp[0 * DD] * mp[0], v1 = vp[1 * DD] * mp[1];
            float v2 = vp[2 * DD] * mp[2], v3 = vp[3 * DD] * mp[3];
            float v4 = vp[4 * DD] * mp[4], v5 = vp[5 * DD] * mp[5];
            float v6 = vp[6 * DD] * mp[6], v7 = vp[7 * DD] * mp[7];
            uint4 w = make_uint4(pkf16(v0, v1), pkf16(v2, v3),
                                 pkf16(v4, v5), pkf16(v6, v7));
            *(uint4*)&Vt_lds[vd][vk0] = w;
        }
        __syncthreads();

        // ---- S^T = K Q^T ----
        f32x4 Sfr[4];
#pragma unroll
        for (int mt = 0; mt < 4; ++mt) {
            f32x4 acc = f32x4{0.f, 0.f, 0.f, 0.f};
#pragma unroll
            for (int kc = 0; kc < 2; ++kc) {
                f16x8 kh = *(const f16x8*)&Kh_lds[mt * 16 + l16][kc * 32 + quad * 8];
                acc = __builtin_amdgcn_mfma_f32_16x16x32_f16(kh, qf[kc], acc, 0, 0, 0);
            }
            Sfr[mt] = acc;   // D[m=key][n=q=l16], pre-scaled (sc in Q)
        }

        // ---- Online softmax: 16 in-lane values (q = l16) ----
        float mx = Sfr[0][0];
#pragma unroll
        for (int mt = 0; mt < 4; ++mt)
#pragma unroll
            for (int r = 0; r < 4; ++r) mx = fmaxf(mx, Sfr[mt][r]);
        mx = fmaxf(mx, __shfl_xor(mx, 16));
        mx = fmaxf(mx, __shfl_xor(mx, 32));

        if (__any(mx > m_run)) {
            const float mnew  = fmaxf(m_run, mx);
            const float alpha = exp2f(m_run - mnew);
            m_run = mnew;
            l_run *= alpha;
#pragma unroll
            for (int mt = 0; mt < 4; ++mt) Ot[mt] *= alpha;
        }

        float ps[4][4];
        float rs = 0.0f;
#pragma unroll
        for (int mt = 0; mt < 4; ++mt)
#pragma unroll
            for (int r = 0; r < 4; ++r) {
                ps[mt][r] = exp2f(Sfr[mt][r] - m_run);
                rs += ps[mt][r];
            }
        rs += __shfl_xor(rs, 16);
        rs += __shfl_xor(rs, 32);
        l_run += rs;

        // ---- P^T -> LDS: packed f16 pairs, 4x ds_write_b64 ----
#pragma unroll
        for (int mt = 0; mt < 4; ++mt) {
            uint2 w = make_uint2(pkf16(ps[mt][0], ps[mt][1]),
                                 pkf16(ps[mt][2], ps[mt][3]));
            *(uint2*)&Pt_lds[wave][l16][mt * 16 + quad * 4] = w;
        }
        // Pt_lds is per-wave private; in-wave RAW handled by lgkmcnt.

        // ---- O^T += V^T P^T ----
#pragma unroll
        for (int kc = 0; kc < 2; ++kc) {
            f16x8 pf = *(const f16x8*)&Pt_lds[wave][l16][kc * 32 + quad * 8];
#pragma unroll
            for (int mt = 0; mt < 4; ++mt) {
                f16x8 vf = *(const f16x8*)&Vt_lds[mt * 16 + l16][kc * 32 + quad * 8];
                Ot[mt] = __builtin_amdgcn_mfma_f32_16x16x32_f16(vf, pf, Ot[mt], 0, 0, 0);
            }
        }
    }

    // ---- Epilogue: O[q][d] = O^T[d][q] / l ----
    const float inv = 1.0f / l_run;
    float* op = Og + base + (size_t)(q0 + l16) * DD + quad * 4;
#pragma unroll
    for (int mt = 0; mt < 4; ++mt) {
#pragma unroll
        for (int r = 0; r < 4; ++r)
            op[mt * 16 + r] = Ot[mt][r] * inv;
    }
}

extern "C" void kernel_launch(void* const* d_in, const int* in_sizes, int n_in,
                              void* d_out, int out_size, void* d_ws, size_t ws_size,
                              hipStream_t stream) {
    const float* Qg = (const float*)d_in[0];
    const float* Kg = (const float*)d_in[1];
    const float* Vg = (const float*)d_in[2];
    // d_in[3] = query_mask (all ones, unused by reference)
    const float* Mg = (const float*)d_in[4];  // key_mask [B,1,1,S]
    const float* Sg = (const float*)d_in[5];  // scale_factor [B,1,1,1]
    // d_in[6] = dropout (0, identity)
    float* Og = (float*)d_out;

    fattn6<<<dim3(BH * QB), dim3(512), 0, stream>>>(Qg, Kg, Vg, Mg, Sg, Og);
}